// Round 5
// baseline (239.474 us; speedup 1.0000x reference)
//
#include <hip/hip_runtime.h>
#include <cstdint>

#define N_IMG 32
#define C_IN 128
#define H_IN 56
#define W_IN 56
#define K_OUT 256
#define HW (H_IN * W_IN)            // 3136
#define M_TOTAL (N_IMG * HW)        // 100352
#define XP_H 58
#define XP_W 58
#define XP_ELEMS (N_IMG * XP_H * XP_W * C_IN)   // 13,778,944 bf16
#define WT_ELEMS (9 * K_OUT * C_IN)             // 294,912 bf16
#define NKT 36                      // K-tiles of 32: 9 rs positions x 4 c-chunks

typedef __bf16 bf16x8 __attribute__((ext_vector_type(8)));
typedef float f32x4 __attribute__((ext_vector_type(4)));

__device__ __align__(16) unsigned short g_xp[XP_ELEMS];  // padded NHWC bf16 input
__device__ __align__(16) unsigned short g_wt[WT_ELEMS];  // wt[rs][k][c] bf16 weights

static __device__ __forceinline__ unsigned short f2bf(float f) {
    unsigned int u = __builtin_bit_cast(unsigned int, f);
    u += 0x7fffu + ((u >> 16) & 1u);   // RNE
    return (unsigned short)(u >> 16);
}

// async global->LDS, 16 bytes per lane; LDS dest = wave-uniform base + lane*16
static __device__ __forceinline__ void async_copy16(const unsigned short* g, unsigned short* l) {
    auto gp = (const __attribute__((address_space(1))) unsigned int*)g;
    auto lp = (__attribute__((address_space(3))) unsigned int*)l;
    __builtin_amdgcn_global_load_lds(gp, lp, 16, 0, 0);
}

// ---------------- prep kernel 1: NCHW fp32 -> padded NHWC bf16 (+border zero) --
__global__ __launch_bounds__(256) void xpose_x(const float* __restrict__ x) {
    __shared__ float tile[C_IN * 57];     // [c][w] padded
    const int h = blockIdx.x;
    const int n = blockIdx.y;
    const int tid = threadIdx.x;

    if (tid < 32) {
        int col = (tid >> 4) * (XP_W - 1);          // 0 or 57
        int q = tid & 15;
        uint4* dst = (uint4*)(g_xp + ((size_t)(n * XP_H + h + 1) * XP_W + col) * C_IN) + q;
        *dst = uint4{0u, 0u, 0u, 0u};
    }
    if (h == 0 || h == H_IN - 1) {
        int hp = (h == 0) ? 0 : XP_H - 1;
        uint4* base = (uint4*)(g_xp + ((size_t)(n * XP_H + hp) * XP_W) * C_IN);
        for (int q = tid; q < (XP_W * C_IN) / 8; q += 256) base[q] = uint4{0u, 0u, 0u, 0u};
    }

#pragma unroll
    for (int i = 0; i < 28; i++) {
        int e = i * 256 + tid;
        int c = e / 56;
        int w = e - c * 56;
        tile[c * 57 + w] = x[((n * C_IN + c) * H_IN + h) * W_IN + w];
    }
    __syncthreads();
    unsigned int* outp = (unsigned int*)g_xp;
#pragma unroll
    for (int i = 0; i < 14; i++) {
        int u = i * 256 + tid;
        int w = u >> 6;
        int cp = u & 63;
        float a = tile[(2 * cp) * 57 + w];
        float b = tile[(2 * cp + 1) * 57 + w];
        unsigned int pk = (unsigned int)f2bf(a) | ((unsigned int)f2bf(b) << 16);
        int idx = ((n * XP_H + h + 1) * XP_W + (w + 1)) * C_IN + 2 * cp;
        outp[idx >> 1] = pk;
    }
}

// ---------------- prep kernel 2: OIHW fp32 -> wt[rs][k][c] bf16 ----------------
__global__ __launch_bounds__(256) void xpose_w(const float* __restrict__ w) {
    int e = blockIdx.x * 256 + threadIdx.x;
    int rr = e >> 15;
    int rem = e & 32767;
    int k = rem >> 7;
    int c = rem & 127;
    g_wt[e] = f2bf(w[(k * C_IN + c) * 9 + rr]);
}

// ---------------- main: implicit-GEMM, 256M x 128N, BK=32, 8 waves -------------
// Round-4 post-mortem fixes:
// (1) swizzle bug: at 64-B rows, bank quad = (row&1)*4 + seg, so the involution
//     must be seg ^= (row>>1)&3 (NOT row&3, which only covers 4 of 8 quads ->
//     the measured exactly-4 conflict cycles/read). Now lanes 0-15 cover all 8
//     quads 2x (2-way = free, m136).
// (2) barrier structure: 3 LDS buffers (72 KB, still 2 blocks/CU) separate the
//     write-after-read hazard by two full iterations -> ONE barrier + one
//     lgkmcnt + one vmcnt per K-step. Iter t: stage t+2 -> buf (t+2)%3 (issued
//     at top, L2 latency hides under reads+MFMA); read buf t%3; MFMA x16;
//     vmcnt(3) retires t+1 (in flight 2 iters); barrier.
__global__ __launch_bounds__(512, 4) void conv_main(float* __restrict__ out) {
    __shared__ __align__(16) unsigned short As[3][8192];   // [buf][256 rows x 32]
    __shared__ __align__(16) unsigned short Bs[3][4096];   // [buf][128 rows x 32]
    const unsigned short* __restrict__ xp = g_xp;
    const unsigned short* __restrict__ wt = g_wt;

    const int tid = threadIdx.x;
    const int wave = tid >> 6, lane = tid & 63;
    const int lr = lane & 15, lq = lane >> 4;
    const int wmL = (wave >> 1) * 64;   // wave m-offset (4 waves in M)
    const int wnL = (wave & 1) * 64;    // wave n-offset (2 waves in N)

    // XCD swizzle, bijective (784 = 8*98); (m-tile, k-half) pairs stay same-XCD
    const int bid = blockIdx.x;
    const int g = (bid & 7) * 98 + (bid >> 3);
    const int m0 = (g >> 1) * 256;
    const int k0 = (g & 1) * 128;

    // staging: A = 1024 units of 16B (su = j*512+tid), B = 512 units (su = tid).
    // unit su -> row=su>>2, seg=su&3; source col pre-swizzled seg^((row>>1)&3)
    // so linear gload_lds dest + swizzled ds_read form the same involution.
    int a_src[2], lds_a[2];
#pragma unroll
    for (int j = 0; j < 2; j++) {
        const int su = j * 512 + tid;
        const int row = su >> 2, seg = su & 3;
        const int sw = (seg ^ ((row >> 1) & 3)) * 8;
        int p = m0 + row;
        int n = p / HW;
        int rem = p - n * HW;
        int h = rem / W_IN;
        int w = rem - h * W_IN;
        a_src[j] = ((n * XP_H + h) * XP_W + w) * C_IN + sw;
        lds_a[j] = (j * 512 + wave * 64) * 8;   // wave-uniform; HW adds lane*16B
    }
    const int brow_s = tid >> 2, bseg = tid & 3;
    const int b_src = (k0 + brow_s) * C_IN + (bseg ^ ((brow_s >> 1) & 3)) * 8;
    const int lds_b = wave * 64 * 8;

    // ds_read swizzled column (shorts); read rows differ from lr only by
    // multiples of 16, so (row>>1)&3 == (lr>>1)&3 for all fragments.
    const int csw = (lq ^ ((lr >> 1) & 3)) * 8;

    // stage full K-tile kt (A 16KB + B 8KB) into buffer nb: 3 loads per thread
    auto stage_tile = [&](int kt, int nb) {
        const int rs = kt >> 2;
        const int r = (rs * 11) >> 5;            // rs/3
        const int sc = rs - r * 3;               // rs%3
        const int aoff = (r * XP_W + sc) * C_IN + (kt & 3) * 32;
        const int boff = rs * (K_OUT * C_IN) + (kt & 3) * 32;
#pragma unroll
        for (int j = 0; j < 2; j++)
            async_copy16(xp + a_src[j] + aoff, &As[nb][lds_a[j]]);
        async_copy16(wt + b_src + boff, &Bs[nb][lds_b]);
    };

    f32x4 acc[4][4];
#pragma unroll
    for (int mi = 0; mi < 4; mi++)
#pragma unroll
        for (int ni = 0; ni < 4; ni++) acc[mi][ni] = f32x4{0.f, 0.f, 0.f, 0.f};

    // prologue: t0 -> buf0, t1 -> buf1; in-order retire => vmcnt(3) means t0 in
    stage_tile(0, 0);
    stage_tile(1, 1);
    asm volatile("s_waitcnt vmcnt(3)" ::: "memory");
    __builtin_amdgcn_s_barrier();
    asm volatile("" ::: "memory");

    for (int tt = 0; tt < NKT / 3; ++tt) {
#pragma unroll
        for (int u = 0; u < 3; u++) {            // buffer indices compile-time
            const int t = tt * 3 + u;
            // stage t+2 into buf (u+2)%3 (read 2 iters ago; end-of-(t-1) barrier
            // proves all waves done). Issue first: L2 fetch starts earliest.
            if (t + 2 < NKT) stage_tile(t + 2, (u + 2) % 3);

            bf16x8 af[4], bfv[4];
#pragma unroll
            for (int mi = 0; mi < 4; mi++)
                af[mi] = *(const bf16x8*)(&As[u][(wmL + mi * 16 + lr) * 32 + csw]);
#pragma unroll
            for (int ni = 0; ni < 4; ni++)
                bfv[ni] = *(const bf16x8*)(&Bs[u][(wnL + ni * 16 + lr) * 32 + csw]);
            asm volatile("s_waitcnt lgkmcnt(0)" ::: "memory");
            __builtin_amdgcn_sched_barrier(0);   // rule 18: pin MFMA below wait
            __builtin_amdgcn_s_setprio(1);
#pragma unroll
            for (int mi = 0; mi < 4; mi++)
#pragma unroll
                for (int ni = 0; ni < 4; ni++)
                    acc[mi][ni] = __builtin_amdgcn_mfma_f32_16x16x32_bf16(
                        af[mi], bfv[ni], acc[mi][ni], 0, 0, 0);
            __builtin_amdgcn_s_setprio(0);
            // retire tile t+1 (issued at iter t-1, ~2 iterations in flight);
            // keep t+2's 3 loads outstanding (never drain mid-loop).
            if (t + 2 < NKT) {
                asm volatile("s_waitcnt vmcnt(3)" ::: "memory");
            } else {
                asm volatile("s_waitcnt vmcnt(0)" ::: "memory");
            }
            __builtin_amdgcn_s_barrier();
            asm volatile("" ::: "memory");
        }
    }

    // epilogue: lane's float4 = 4 consecutive pixels at fixed out-channel k
#pragma unroll
    for (int mi = 0; mi < 4; mi++) {
        int p = m0 + wmL + mi * 16 + lq * 4;   // mult of 4; 3136%4==0 -> same n
        int n = p / HW;
        int off = p - n * HW;
#pragma unroll
        for (int ni = 0; ni < 4; ni++) {
            int k = k0 + wnL + ni * 16 + lr;
            *(f32x4*)(out + (n * K_OUT + k) * HW + off) = acc[mi][ni];
        }
    }
}

extern "C" void kernel_launch(void* const* d_in, const int* in_sizes, int n_in,
                              void* d_out, int out_size, void* d_ws, size_t ws_size,
                              hipStream_t stream) {
    const float* x = (const float*)d_in[0];
    const float* w = (const float*)d_in[1];
    float* out = (float*)d_out;

    hipLaunchKernelGGL(xpose_x, dim3(H_IN, N_IMG), dim3(256), 0, stream, x);
    hipLaunchKernelGGL(xpose_w, dim3(WT_ELEMS / 256), dim3(256), 0, stream, w);
    hipLaunchKernelGGL(conv_main, dim3((M_TOTAL / 256) * (K_OUT / 128)), dim3(512), 0, stream, out);
}

// Round 6
// 237.819 us; speedup vs baseline: 1.0070x; 1.0070x over previous
//
#include <hip/hip_runtime.h>
#include <cstdint>

#define N_IMG 32
#define C_IN 128
#define H_IN 56
#define W_IN 56
#define K_OUT 256
#define HW (H_IN * W_IN)            // 3136
#define M_TOTAL (N_IMG * HW)        // 100352
#define XP_H 58
#define XP_W 58
#define XP_ELEMS (N_IMG * XP_H * XP_W * C_IN)   // 13,778,944 bf16
#define WT_ELEMS (9 * K_OUT * C_IN)             // 294,912 bf16
#define NKT 36                      // K-tiles of 32: 9 rs positions x 4 c-chunks

typedef __bf16 bf16x8 __attribute__((ext_vector_type(8)));
typedef float f32x4 __attribute__((ext_vector_type(4)));
typedef float f32x16 __attribute__((ext_vector_type(16)));

__device__ __align__(16) unsigned short g_xp[XP_ELEMS];  // padded NHWC bf16 input
__device__ __align__(16) unsigned short g_wt[WT_ELEMS];  // wt[rs][k][c] bf16 weights

static __device__ __forceinline__ unsigned short f2bf(float f) {
    unsigned int u = __builtin_bit_cast(unsigned int, f);
    u += 0x7fffu + ((u >> 16) & 1u);   // RNE
    return (unsigned short)(u >> 16);
}

// async global->LDS, 16 bytes per lane; LDS dest = wave-uniform base + lane*16
static __device__ __forceinline__ void async_copy16(const unsigned short* g, unsigned short* l) {
    auto gp = (const __attribute__((address_space(1))) unsigned int*)g;
    auto lp = (__attribute__((address_space(3))) unsigned int*)l;
    __builtin_amdgcn_global_load_lds(gp, lp, 16, 0, 0);
}

// ---------------- prep kernel 1: NCHW fp32 -> padded NHWC bf16 (+border zero) --
__global__ __launch_bounds__(256) void xpose_x(const float* __restrict__ x) {
    __shared__ float tile[C_IN * 57];     // [c][w] padded
    const int h = blockIdx.x;
    const int n = blockIdx.y;
    const int tid = threadIdx.x;

    if (tid < 32) {
        int col = (tid >> 4) * (XP_W - 1);          // 0 or 57
        int q = tid & 15;
        uint4* dst = (uint4*)(g_xp + ((size_t)(n * XP_H + h + 1) * XP_W + col) * C_IN) + q;
        *dst = uint4{0u, 0u, 0u, 0u};
    }
    if (h == 0 || h == H_IN - 1) {
        int hp = (h == 0) ? 0 : XP_H - 1;
        uint4* base = (uint4*)(g_xp + ((size_t)(n * XP_H + hp) * XP_W) * C_IN);
        for (int q = tid; q < (XP_W * C_IN) / 8; q += 256) base[q] = uint4{0u, 0u, 0u, 0u};
    }

#pragma unroll
    for (int i = 0; i < 28; i++) {
        int e = i * 256 + tid;
        int c = e / 56;
        int w = e - c * 56;
        tile[c * 57 + w] = x[((n * C_IN + c) * H_IN + h) * W_IN + w];
    }
    __syncthreads();
    unsigned int* outp = (unsigned int*)g_xp;
#pragma unroll
    for (int i = 0; i < 14; i++) {
        int u = i * 256 + tid;
        int w = u >> 6;
        int cp = u & 63;
        float a = tile[(2 * cp) * 57 + w];
        float b = tile[(2 * cp + 1) * 57 + w];
        unsigned int pk = (unsigned int)f2bf(a) | ((unsigned int)f2bf(b) << 16);
        int idx = ((n * XP_H + h + 1) * XP_W + (w + 1)) * C_IN + 2 * cp;
        outp[idx >> 1] = pk;
    }
}

// ---------------- prep kernel 2: OIHW fp32 -> wt[rs][k][c] bf16 ----------------
__global__ __launch_bounds__(256) void xpose_w(const float* __restrict__ w) {
    int e = blockIdx.x * 256 + threadIdx.x;
    int rr = e >> 15;
    int rem = e & 32767;
    int k = rem >> 7;
    int c = rem & 127;
    g_wt[e] = f2bf(w[(k * C_IN + c) * 9 + rr]);
}

// ---------------- main: implicit-GEMM, 256M x 128N, BK=32, 8 waves -------------
// Round-5 post-mortem: four sync structures all hit 112-115 us / MfmaUtil 21%.
// Shared culprit = my per-iter schedule pinning (lgkmcnt(0)+sched_barrier+
// setprio) forcing {all reads -> drain -> all MFMA} convoys per wave -- the
// measured m141 failure (874->510 TF). This version:
//  (1) NO pinning: only structural sync (raw barrier + counted vmcnt + compiler
//      fences at barrier boundaries). Compiler emits counted lgkm interleave.
//  (2) 32x32x16 MFMA: same LDS traffic, half the MFMA instrs, +15% pipe ceiling
//      (m119), deeper per-inst latency tolerance.
// 3 LDS buffers (72 KB, 2 blocks/CU): write-after-read separated by 2 iters.
// Iter t: stage t+2 -> buf (t+2)%3; read buf t%3; 8 MFMA; vmcnt(3) retires
// tile t+1 (in flight ~2 iters); barrier. Never drains to 0 mid-loop (T4).
__global__ __launch_bounds__(512, 4) void conv_main(float* __restrict__ out) {
    __shared__ __align__(16) unsigned short As[3][8192];   // [buf][256 rows x 32]
    __shared__ __align__(16) unsigned short Bs[3][4096];   // [buf][128 rows x 32]
    const unsigned short* __restrict__ xp = g_xp;
    const unsigned short* __restrict__ wt = g_wt;

    const int tid = threadIdx.x;
    const int wave = tid >> 6, lane = tid & 63;
    const int lane5 = lane & 31;        // row within 32 (MFMA operand row/col)
    const int hl = lane >> 5;           // lane half: k-subcolumn selector
    const int swl = (lane >> 1) & 3;    // swizzle term = bits 1-2 of row
    const int wmL = (wave >> 1) * 64;   // wave m-offset (4 waves in M)
    const int wnL = (wave & 1) * 64;    // wave n-offset (2 waves in N)

    // XCD swizzle, bijective (784 = 8*98); (m-tile, k-half) pairs stay same-XCD
    const int bid = blockIdx.x;
    const int g = (bid & 7) * 98 + (bid >> 3);
    const int m0 = (g >> 1) * 256;
    const int k0 = (g & 1) * 128;

    // staging: A = 1024 units of 16B (su = j*512+tid), B = 512 units (su = tid).
    // unit su -> row=su>>2, seg=su&3; source col pre-swizzled seg^((row>>1)&3)
    // (64-B rows: bank quad = (row&1)*4+seg) so linear gload_lds dest + swizzled
    // ds_read form the same involution. Verified: conflicts = 0 (round 5).
    int a_src[2], lds_a[2];
#pragma unroll
    for (int j = 0; j < 2; j++) {
        const int su = j * 512 + tid;
        const int row = su >> 2, seg = su & 3;
        const int sw = (seg ^ ((row >> 1) & 3)) * 8;
        int p = m0 + row;
        int n = p / HW;
        int rem = p - n * HW;
        int h = rem / W_IN;
        int w = rem - h * W_IN;
        a_src[j] = ((n * XP_H + h) * XP_W + w) * C_IN + sw;
        lds_a[j] = (j * 512 + wave * 64) * 8;   // wave-uniform; HW adds lane*16B
    }
    const int brow_s = tid >> 2, bseg = tid & 3;
    const int b_src = (k0 + brow_s) * C_IN + (bseg ^ ((brow_s >> 1) & 3)) * 8;
    const int lds_b = wave * 64 * 8;

    // ds_read columns (shorts): logical 16B-slot s = 2*ks + hl, stored s ^ swl
    int acol[2];
#pragma unroll
    for (int ks = 0; ks < 2; ks++)
        acol[ks] = ((2 * ks + hl) ^ swl) * 8;
    const int arow0 = (wmL + lane5) * 32;
    const int brow0 = (wnL + lane5) * 32;

    // stage full K-tile kt (A 16KB + B 8KB) into buffer nb: 3 loads per thread
    auto stage_tile = [&](int kt, int nb) {
        const int rs = kt >> 2;
        const int r = (rs * 11) >> 5;            // rs/3
        const int sc = rs - r * 3;               // rs%3
        const int aoff = (r * XP_W + sc) * C_IN + (kt & 3) * 32;
        const int boff = rs * (K_OUT * C_IN) + (kt & 3) * 32;
#pragma unroll
        for (int j = 0; j < 2; j++)
            async_copy16(xp + a_src[j] + aoff, &As[nb][lds_a[j]]);
        async_copy16(wt + b_src + boff, &Bs[nb][lds_b]);
    };

    f32x16 acc[2][2];
#pragma unroll
    for (int mf = 0; mf < 2; mf++)
#pragma unroll
        for (int nf = 0; nf < 2; nf++) acc[mf][nf] = (f32x16)(0.f);

    // prologue: t0 -> buf0, t1 -> buf1; in-order retire => vmcnt(3) means t0 in
    stage_tile(0, 0);
    stage_tile(1, 1);
    asm volatile("s_waitcnt vmcnt(3)" ::: "memory");
    __builtin_amdgcn_s_barrier();
    asm volatile("" ::: "memory");

    for (int tt = 0; tt < NKT / 3; ++tt) {
#pragma unroll
        for (int u = 0; u < 3; u++) {            // buffer indices compile-time
            const int t = tt * 3 + u;
            // stage t+2 into buf (u+2)%3 (read finished 2 iters ago)
            if (t + 2 < NKT) stage_tile(t + 2, (u + 2) % 3);

            bf16x8 af[2][2], bfv[2][2];
#pragma unroll
            for (int mf = 0; mf < 2; mf++)
#pragma unroll
                for (int ks = 0; ks < 2; ks++)
                    af[mf][ks] = *(const bf16x8*)(&As[u][arow0 + mf * 1024 + acol[ks]]);
#pragma unroll
            for (int nf = 0; nf < 2; nf++)
#pragma unroll
                for (int ks = 0; ks < 2; ks++)
                    bfv[nf][ks] = *(const bf16x8*)(&Bs[u][brow0 + nf * 1024 + acol[ks]]);
            // no lgkmcnt(0)/sched_barrier/setprio: compiler interleaves reads
            // with MFMAs via counted lgkm waits (m97 r109; m141 anti-lesson).
#pragma unroll
            for (int ks = 0; ks < 2; ks++)
#pragma unroll
                for (int mf = 0; mf < 2; mf++)
#pragma unroll
                    for (int nf = 0; nf < 2; nf++)
                        acc[mf][nf] = __builtin_amdgcn_mfma_f32_32x32x16_bf16(
                            af[mf][ks], bfv[nf][ks], acc[mf][nf], 0, 0, 0);
            // retire tile t+1 (issued at iter t-1); keep t+2's loads in flight
            if (t + 2 < NKT) {
                asm volatile("s_waitcnt vmcnt(3)" ::: "memory");
            } else {
                asm volatile("s_waitcnt vmcnt(0)" ::: "memory");
            }
            __builtin_amdgcn_s_barrier();
            asm volatile("" ::: "memory");
        }
    }

    // epilogue: C/D 32x32 layout (m74/m101): col=lane&31, row=(r&3)+8(r>>2)+4hl
    // -> reg group 4g..4g+3 = 4 consecutive pixels at fixed out-channel k.
#pragma unroll
    for (int mf = 0; mf < 2; mf++)
#pragma unroll
        for (int nf = 0; nf < 2; nf++)
#pragma unroll
            for (int gq = 0; gq < 4; gq++) {
                int p = m0 + wmL + mf * 32 + 8 * gq + 4 * hl;  // mult of 4
                int n = p / HW;
                int off = p - n * HW;
                int k = k0 + wnL + nf * 32 + lane5;
                f32x4 v = {acc[mf][nf][4 * gq + 0], acc[mf][nf][4 * gq + 1],
                           acc[mf][nf][4 * gq + 2], acc[mf][nf][4 * gq + 3]};
                *(f32x4*)(out + (n * K_OUT + k) * HW + off) = v;
            }
}

extern "C" void kernel_launch(void* const* d_in, const int* in_sizes, int n_in,
                              void* d_out, int out_size, void* d_ws, size_t ws_size,
                              hipStream_t stream) {
    const float* x = (const float*)d_in[0];
    const float* w = (const float*)d_in[1];
    float* out = (float*)d_out;

    hipLaunchKernelGGL(xpose_x, dim3(H_IN, N_IMG), dim3(256), 0, stream, x);
    hipLaunchKernelGGL(xpose_w, dim3(WT_ELEMS / 256), dim3(256), 0, stream, w);
    hipLaunchKernelGGL(conv_main, dim3((M_TOTAL / 256) * (K_OUT / 128)), dim3(512), 0, stream, out);
}

// Round 7
// 227.937 us; speedup vs baseline: 1.0506x; 1.0434x over previous
//
#include <hip/hip_runtime.h>
#include <cstdint>

#define N_IMG 32
#define C_IN 128
#define H_IN 56
#define W_IN 56
#define K_OUT 256
#define HW (H_IN * W_IN)            // 3136
#define M_TOTAL (N_IMG * HW)        // 100352
#define XP_H 58
#define XP_W 58
#define XP_ELEMS (N_IMG * XP_H * XP_W * C_IN)   // 13,778,944 bf16
#define WT_ELEMS (9 * K_OUT * C_IN)             // 294,912 bf16
#define NKT 36                      // K-steps of 32: 9 rs positions x 4 c-chunks
#define BM 224                      // 4 h-rows of one image (3136/224 = 14 exact)
#define PATCH_PIX (6 * XP_W)        // 348 padded pixels (6 halo rows x 58)
#define PATCH_SHORTS (PATCH_PIX * C_IN)   // 44544 shorts = 87 KiB
#define PATCH_UNITS (PATCH_SHORTS / 8)    // 5568 16B-units

typedef __bf16 bf16x8 __attribute__((ext_vector_type(8)));
typedef float f32x4 __attribute__((ext_vector_type(4)));

__device__ __align__(16) unsigned short g_xp[XP_ELEMS];  // padded NHWC bf16 input
__device__ __align__(16) unsigned short g_wt[WT_ELEMS];  // wt[rs][k][c] bf16 weights

static __device__ __forceinline__ unsigned short f2bf(float f) {
    unsigned int u = __builtin_bit_cast(unsigned int, f);
    u += 0x7fffu + ((u >> 16) & 1u);   // RNE
    return (unsigned short)(u >> 16);
}

// async global->LDS, 16 bytes per lane; LDS dest = wave-uniform base + lane*16
static __device__ __forceinline__ void async_copy16(const unsigned short* g, unsigned short* l) {
    auto gp = (const __attribute__((address_space(1))) unsigned int*)g;
    auto lp = (__attribute__((address_space(3))) unsigned int*)l;
    __builtin_amdgcn_global_load_lds(gp, lp, 16, 0, 0);
}

// ---------------- prep kernel 1: NCHW fp32 -> padded NHWC bf16 (+border zero) --
__global__ __launch_bounds__(256) void xpose_x(const float* __restrict__ x) {
    __shared__ float tile[C_IN * 57];     // [c][w] padded
    const int h = blockIdx.x;
    const int n = blockIdx.y;
    const int tid = threadIdx.x;

    if (tid < 32) {
        int col = (tid >> 4) * (XP_W - 1);          // 0 or 57
        int q = tid & 15;
        uint4* dst = (uint4*)(g_xp + ((size_t)(n * XP_H + h + 1) * XP_W + col) * C_IN) + q;
        *dst = uint4{0u, 0u, 0u, 0u};
    }
    if (h == 0 || h == H_IN - 1) {
        int hp = (h == 0) ? 0 : XP_H - 1;
        uint4* base = (uint4*)(g_xp + ((size_t)(n * XP_H + hp) * XP_W) * C_IN);
        for (int q = tid; q < (XP_W * C_IN) / 8; q += 256) base[q] = uint4{0u, 0u, 0u, 0u};
    }

#pragma unroll
    for (int i = 0; i < 28; i++) {
        int e = i * 256 + tid;
        int c = e / 56;
        int w = e - c * 56;
        tile[c * 57 + w] = x[((n * C_IN + c) * H_IN + h) * W_IN + w];
    }
    __syncthreads();
    unsigned int* outp = (unsigned int*)g_xp;
#pragma unroll
    for (int i = 0; i < 14; i++) {
        int u = i * 256 + tid;
        int w = u >> 6;
        int cp = u & 63;
        float a = tile[(2 * cp) * 57 + w];
        float b = tile[(2 * cp + 1) * 57 + w];
        unsigned int pk = (unsigned int)f2bf(a) | ((unsigned int)f2bf(b) << 16);
        int idx = ((n * XP_H + h + 1) * XP_W + (w + 1)) * C_IN + 2 * cp;
        outp[idx >> 1] = pk;
    }
}

// ---------------- prep kernel 2: OIHW fp32 -> wt[rs][k][c] bf16 ----------------
__global__ __launch_bounds__(256) void xpose_w(const float* __restrict__ w) {
    int e = blockIdx.x * 256 + threadIdx.x;
    int rr = e >> 15;
    int rem = e & 32767;
    int k = rem >> 7;
    int c = rem & 127;
    g_wt[e] = f2bf(w[(k * C_IN + c) * 9 + rr]);
}

// ---------------- main: halo-resident-A implicit GEMM ------------------------
// Round-6 post-mortem: six schedules all 112-117us -> the invariant is the
// BYTES, not the schedule (per-iter re-staging moves ~677MB through L2/L3).
// Conv-specific fix: the 9 rs positions reuse the same input, so stage the raw
// 6-row halo patch (87KB) ONCE per block; im2col happens at ds_read address
// time (per-lane pixel base + wave-uniform rs offset). A-staging 451MB -> 39MB.
//  - Block: BM=224 pixels (4 h-rows, image-aligned), BN=256 (all outch). 448 blk.
//  - 8 waves, wave-tile 112x64: mf=7, nf=4, 16x16x32 MFMA, acc 112 VGPR.
//  - B: 4-deep LDS ring (16KB tiles), staged via global_load_lds from
//    L2-resident g_wt; ONE barrier/iter; counted vmcnt(4) (never drains).
//    Ring write(t+3) vs read(t-1) distance 3 > 1-iter max wave drift -> safe;
//    reads complete before barrier via MFMA data-deps (no lgkm drain needed).
//  - Swizzles (both-sides involution, rule 21): A source ^(pix&7) over 16 slots,
//    read slot = octet ^ (pix&7); B = R5-proven ^((row>>1)&3) over 4 slots.
// LDS 87+64 = 151KB -> 1 block/CU (8 waves). No pinning (m141 anti-lesson).
__global__ __launch_bounds__(512, 2) void conv_main(float* __restrict__ out) {
    __shared__ __align__(16) unsigned short patch[PATCH_SHORTS];
    __shared__ __align__(16) unsigned short Bs[4 * 8192];
    const unsigned short* __restrict__ xp = g_xp;
    const unsigned short* __restrict__ wt = g_wt;

    const int tid = threadIdx.x;
    const int wave = tid >> 6, lane = tid & 63;
    const int lr = lane & 15, lq = lane >> 4;
    const int wm0 = (wave & 1) * 112;    // 2 waves in M
    const int wn0 = (wave >> 1) * 64;    // 4 waves in N

    // XCD-aware bijective swizzle: 448 = 8 * 56
    const int bid = blockIdx.x;
    const int gq = (bid & 7) * 56 + (bid >> 3);
    const int m0 = gq * 224;
    const int n_img = gq / 14;            // image (uniform for whole block)
    const int hb = (gq - n_img * 14) * 4; // first output h-row of this block

    // per-lane A pixel bases: patch-local padded pixel index of output pixel
    int qb[7];
#pragma unroll
    for (int mi = 0; mi < 7; mi++) {
        int pp = wm0 + mi * 16 + lr;                 // 0..223
        qb[mi] = (pp / 56 + 1) * XP_W + (pp % 56 + 1);
    }

    // B staging constants: unit u = i*512+tid -> row=u>>2, sl=u&3
    const int brow = tid >> 2, bsl = tid & 3;
    const int b_srco  = brow * C_IN + ((bsl ^ ((brow >> 1) & 3)) * 8);
    const int b_srco2 = (128 + brow) * C_IN + ((bsl ^ (((128 + brow) >> 1) & 3)) * 8);
    const int b_ldso = wave * 64 * 8;     // wave-uniform; HW adds lane*16B

    auto stage_B = [&](int kt) {          // 2 global_load_lds per thread
        const unsigned short* src = wt + (kt >> 2) * (K_OUT * C_IN) + (kt & 3) * 32;
        unsigned short* dst = &Bs[(kt & 3) * 8192];
        async_copy16(src + b_srco,  dst + b_ldso);
        async_copy16(src + b_srco2, dst + 4096 + b_ldso);
    };

    // B ds_read swizzled column (shorts), R5-proven involution
    const int bswz = (lq ^ ((lr >> 1) & 3)) * 8;

    // ---- prologue: patch (once) + B0..B2 ----
    const size_t srcx = (size_t)(n_img * XP_H + hb) * XP_W * C_IN;
#pragma unroll
    for (int i = 0; i < 11; i++) {
        if (i < 10 || wave < 7) {          // wave-uniform guard (5568 = 10*512+448)
            int u = i * 512 + tid;
            int ppix = u >> 4, sl = u & 15;
            async_copy16(xp + srcx + ppix * C_IN + ((sl ^ (ppix & 7)) * 8),
                         &patch[(i * 512 + wave * 64) * 8]);
        }
    }
    stage_B(0); stage_B(1); stage_B(2);
    asm volatile("s_waitcnt vmcnt(4)" ::: "memory");   // patch + B0 landed
    __builtin_amdgcn_s_barrier();
    asm volatile("" ::: "memory");

    f32x4 acc[7][4];
#pragma unroll
    for (int mi = 0; mi < 7; mi++)
#pragma unroll
        for (int nf = 0; nf < 4; nf++) acc[mi][nf] = f32x4{0.f, 0.f, 0.f, 0.f};

    for (int t = 0; t < NKT; ++t) {
        if (t + 3 < NKT) stage_B(t + 3);   // into ring slot (t+3)&3

        // wave-uniform rs offset into the patch: dq = (r-1)*58 + (s-1)
        const int rs = t >> 2;
        const int r = (rs * 11) >> 5;      // rs/3
        const int s = rs - r * 3;          // rs%3
        const int dq = r * XP_W + s - (XP_W + 1);
        const int so = (t & 3) * 4 + lq;   // logical channel-octet index (0..15)

        bf16x8 bfv[4];
#pragma unroll
        for (int nf = 0; nf < 4; nf++)
            bfv[nf] = *(const bf16x8*)(&Bs[(t & 3) * 8192 + (wn0 + nf * 16 + lr) * 32 + bswz]);
        bf16x8 af[7];
#pragma unroll
        for (int mi = 0; mi < 7; mi++) {
            int qq = qb[mi] + dq;
            af[mi] = *(const bf16x8*)(&patch[qq * C_IN + ((so ^ (qq & 7)) * 8)]);
        }
        // no pinning: compiler interleaves ds_read/MFMA with counted lgkm waits
#pragma unroll
        for (int mi = 0; mi < 7; mi++)
#pragma unroll
            for (int nf = 0; nf < 4; nf++)
                acc[mi][nf] = __builtin_amdgcn_mfma_f32_16x16x32_bf16(
                    af[mi], bfv[nf], acc[mi][nf], 0, 0, 0);

        // counted retire: own B(t+1) pair landed; keep newer pairs in flight
        if (t < NKT - 3) {
            asm volatile("s_waitcnt vmcnt(4)" ::: "memory");
        } else if (t == NKT - 3) {
            asm volatile("s_waitcnt vmcnt(2)" ::: "memory");
        } else {
            asm volatile("s_waitcnt vmcnt(0)" ::: "memory");
        }
        __builtin_amdgcn_s_barrier();      // bounds drift to <1 iter (ring dist 3)
        asm volatile("" ::: "memory");
    }

    // epilogue: verified 16x16 C layout; n uniform per block (image-aligned BM)
    const int off0 = m0 - n_img * HW;
#pragma unroll
    for (int mi = 0; mi < 7; mi++) {
        int off = off0 + wm0 + mi * 16 + lq * 4;    // multiple of 4
#pragma unroll
        for (int nf = 0; nf < 4; nf++) {
            int k = wn0 + nf * 16 + lr;
            *(f32x4*)(out + ((size_t)(n_img * K_OUT + k)) * HW + off) = acc[mi][nf];
        }
    }
}

extern "C" void kernel_launch(void* const* d_in, const int* in_sizes, int n_in,
                              void* d_out, int out_size, void* d_ws, size_t ws_size,
                              hipStream_t stream) {
    const float* x = (const float*)d_in[0];
    const float* w = (const float*)d_in[1];
    float* out = (float*)d_out;

    hipLaunchKernelGGL(xpose_x, dim3(H_IN, N_IMG), dim3(256), 0, stream, x);
    hipLaunchKernelGGL(xpose_w, dim3(WT_ELEMS / 256), dim3(256), 0, stream, w);
    hipLaunchKernelGGL(conv_main, dim3(M_TOTAL / BM), dim3(512), 0, stream, out);
}

// Round 8
// 221.204 us; speedup vs baseline: 1.0826x; 1.0304x over previous
//
#include <hip/hip_runtime.h>
#include <cstdint>

#define N_IMG 32
#define C_IN 128
#define H_IN 56
#define W_IN 56
#define K_OUT 256
#define HW (H_IN * W_IN)            // 3136
#define M_TOTAL (N_IMG * HW)        // 100352
#define XP_H 58
#define XP_W 58
#define XP_ELEMS (N_IMG * XP_H * XP_W * C_IN)   // 13,778,944 bf16
#define WT_ELEMS (9 * K_OUT * C_IN)             // 294,912 bf16
#define NKT 36                      // K-steps of 32: 9 rs positions x 4 c-chunks
#define BM 224                      // 4 h-rows of one image (3136/224 = 14 exact)
#define PATCH_PIX (6 * XP_W)        // 348 padded pixels (6 halo rows x 58)
#define PATCH_SHORTS (PATCH_PIX * C_IN)   // 44544 shorts = 87 KiB

typedef __bf16 bf16x8 __attribute__((ext_vector_type(8)));
typedef float f32x4 __attribute__((ext_vector_type(4)));

// fallback storage if workspace is too small (harness restores these = ~120us
// of re-poison dispatches per iteration; d_ws path avoids that).
__device__ __align__(16) unsigned short g_xp[XP_ELEMS];
__device__ __align__(16) unsigned short g_wt[WT_ELEMS];

static __device__ __forceinline__ unsigned short f2bf(float f) {
    unsigned int u = __builtin_bit_cast(unsigned int, f);
    u += 0x7fffu + ((u >> 16) & 1u);   // RNE
    return (unsigned short)(u >> 16);
}

// async global->LDS, 16 bytes per lane; LDS dest = wave-uniform base + lane*16
static __device__ __forceinline__ void async_copy16(const unsigned short* g, unsigned short* l) {
    auto gp = (const __attribute__((address_space(1))) unsigned int*)g;
    auto lp = (__attribute__((address_space(3))) unsigned int*)l;
    __builtin_amdgcn_global_load_lds(gp, lp, 16, 0, 0);
}

// ---------------- prep kernel 1: NCHW fp32 -> padded NHWC bf16 (+border zero) --
__global__ __launch_bounds__(256) void xpose_x(const float* __restrict__ x,
                                               unsigned short* __restrict__ xp_in) {
    unsigned short* xp = xp_in ? xp_in : g_xp;   // uniform branch
    __shared__ float tile[C_IN * 57];     // [c][w] padded
    const int h = blockIdx.x;
    const int n = blockIdx.y;
    const int tid = threadIdx.x;

    if (tid < 32) {
        int col = (tid >> 4) * (XP_W - 1);          // 0 or 57
        int q = tid & 15;
        uint4* dst = (uint4*)(xp + ((size_t)(n * XP_H + h + 1) * XP_W + col) * C_IN) + q;
        *dst = uint4{0u, 0u, 0u, 0u};
    }
    if (h == 0 || h == H_IN - 1) {
        int hp = (h == 0) ? 0 : XP_H - 1;
        uint4* base = (uint4*)(xp + ((size_t)(n * XP_H + hp) * XP_W) * C_IN);
        for (int q = tid; q < (XP_W * C_IN) / 8; q += 256) base[q] = uint4{0u, 0u, 0u, 0u};
    }

#pragma unroll
    for (int i = 0; i < 28; i++) {
        int e = i * 256 + tid;
        int c = e / 56;
        int w = e - c * 56;
        tile[c * 57 + w] = x[((n * C_IN + c) * H_IN + h) * W_IN + w];
    }
    __syncthreads();
    unsigned int* outp = (unsigned int*)xp;
#pragma unroll
    for (int i = 0; i < 14; i++) {
        int u = i * 256 + tid;
        int w = u >> 6;
        int cp = u & 63;
        float a = tile[(2 * cp) * 57 + w];
        float b = tile[(2 * cp + 1) * 57 + w];
        unsigned int pk = (unsigned int)f2bf(a) | ((unsigned int)f2bf(b) << 16);
        int idx = ((n * XP_H + h + 1) * XP_W + (w + 1)) * C_IN + 2 * cp;
        outp[idx >> 1] = pk;
    }
}

// ---------------- prep kernel 2: OIHW fp32 -> wt[rs][k][c] bf16 ----------------
__global__ __launch_bounds__(256) void xpose_w(const float* __restrict__ w,
                                               unsigned short* __restrict__ wt_in) {
    unsigned short* wt = wt_in ? wt_in : g_wt;   // uniform branch
    int e = blockIdx.x * 256 + threadIdx.x;
    int rr = e >> 15;
    int rem = e & 32767;
    int k = rem >> 7;
    int c = rem & 127;
    wt[e] = f2bf(w[(k * C_IN + c) * 9 + rr]);
}

// ---------------- main: halo-resident-A implicit GEMM (identical to round 7) ---
// Round-7 post-mortem: true matrix-pipe util ~7% (MfmaUtil counts in-flight
// latency, not pipe-busy); no pipe saturated; per-iter cost ~3800cy vs ~1300
// modeled. Algorithm kept byte-identical this round; the ONE change is the
// xp/wt storage moving to d_ws (kills the harness's ~120us/iter restore of
// mutated __device__ globals). Attribution: conv_main counters must not move.
__global__ __launch_bounds__(512, 2) void conv_main(float* __restrict__ out,
                                                    const unsigned short* __restrict__ xp_in,
                                                    const unsigned short* __restrict__ wt_in) {
    __shared__ __align__(16) unsigned short patch[PATCH_SHORTS];
    __shared__ __align__(16) unsigned short Bs[4 * 8192];
    const unsigned short* __restrict__ xp = xp_in ? xp_in : g_xp;
    const unsigned short* __restrict__ wt = wt_in ? wt_in : g_wt;

    const int tid = threadIdx.x;
    const int wave = tid >> 6, lane = tid & 63;
    const int lr = lane & 15, lq = lane >> 4;
    const int wm0 = (wave & 1) * 112;    // 2 waves in M
    const int wn0 = (wave >> 1) * 64;    // 4 waves in N

    // XCD-aware bijective swizzle: 448 = 8 * 56
    const int bid = blockIdx.x;
    const int gq = (bid & 7) * 56 + (bid >> 3);
    const int m0 = gq * 224;
    const int n_img = gq / 14;            // image (uniform for whole block)
    const int hb = (gq - n_img * 14) * 4; // first output h-row of this block

    // per-lane A pixel bases: patch-local padded pixel index of output pixel
    int qb[7];
#pragma unroll
    for (int mi = 0; mi < 7; mi++) {
        int pp = wm0 + mi * 16 + lr;                 // 0..223
        qb[mi] = (pp / 56 + 1) * XP_W + (pp % 56 + 1);
    }

    // B staging constants: unit u = i*512+tid -> row=u>>2, sl=u&3
    const int brow = tid >> 2, bsl = tid & 3;
    const int b_srco  = brow * C_IN + ((bsl ^ ((brow >> 1) & 3)) * 8);
    const int b_srco2 = (128 + brow) * C_IN + ((bsl ^ (((128 + brow) >> 1) & 3)) * 8);
    const int b_ldso = wave * 64 * 8;     // wave-uniform; HW adds lane*16B

    auto stage_B = [&](int kt) {          // 2 global_load_lds per thread
        const unsigned short* src = wt + (kt >> 2) * (K_OUT * C_IN) + (kt & 3) * 32;
        unsigned short* dst = &Bs[(kt & 3) * 8192];
        async_copy16(src + b_srco,  dst + b_ldso);
        async_copy16(src + b_srco2, dst + 4096 + b_ldso);
    };

    // B ds_read swizzled column (shorts), R5-proven involution
    const int bswz = (lq ^ ((lr >> 1) & 3)) * 8;

    // ---- prologue: patch (once) + B0..B2 ----
    const size_t srcx = (size_t)(n_img * XP_H + hb) * XP_W * C_IN;
#pragma unroll
    for (int i = 0; i < 11; i++) {
        if (i < 10 || wave < 7) {          // wave-uniform guard (5568 = 10*512+448)
            int u = i * 512 + tid;
            int ppix = u >> 4, sl = u & 15;
            async_copy16(xp + srcx + ppix * C_IN + ((sl ^ (ppix & 7)) * 8),
                         &patch[(i * 512 + wave * 64) * 8]);
        }
    }
    stage_B(0); stage_B(1); stage_B(2);
    asm volatile("s_waitcnt vmcnt(4)" ::: "memory");   // patch + B0 landed
    __builtin_amdgcn_s_barrier();
    asm volatile("" ::: "memory");

    f32x4 acc[7][4];
#pragma unroll
    for (int mi = 0; mi < 7; mi++)
#pragma unroll
        for (int nf = 0; nf < 4; nf++) acc[mi][nf] = f32x4{0.f, 0.f, 0.f, 0.f};

    for (int t = 0; t < NKT; ++t) {
        if (t + 3 < NKT) stage_B(t + 3);   // into ring slot (t+3)&3

        // wave-uniform rs offset into the patch: dq = (r-1)*58 + (s-1)
        const int rs = t >> 2;
        const int r = (rs * 11) >> 5;      // rs/3
        const int s = rs - r * 3;          // rs%3
        const int dq = r * XP_W + s - (XP_W + 1);
        const int so = (t & 3) * 4 + lq;   // logical channel-octet index (0..15)

        bf16x8 bfv[4];
#pragma unroll
        for (int nf = 0; nf < 4; nf++)
            bfv[nf] = *(const bf16x8*)(&Bs[(t & 3) * 8192 + (wn0 + nf * 16 + lr) * 32 + bswz]);
        bf16x8 af[7];
#pragma unroll
        for (int mi = 0; mi < 7; mi++) {
            int qq = qb[mi] + dq;
            af[mi] = *(const bf16x8*)(&patch[qq * C_IN + ((so ^ (qq & 7)) * 8)]);
        }
        // no pinning: compiler interleaves ds_read/MFMA with counted lgkm waits
#pragma unroll
        for (int mi = 0; mi < 7; mi++)
#pragma unroll
            for (int nf = 0; nf < 4; nf++)
                acc[mi][nf] = __builtin_amdgcn_mfma_f32_16x16x32_bf16(
                    af[mi], bfv[nf], acc[mi][nf], 0, 0, 0);

        // counted retire: own B(t+1) pair landed; keep newer pairs in flight
        if (t < NKT - 3) {
            asm volatile("s_waitcnt vmcnt(4)" ::: "memory");
        } else if (t == NKT - 3) {
            asm volatile("s_waitcnt vmcnt(2)" ::: "memory");
        } else {
            asm volatile("s_waitcnt vmcnt(0)" ::: "memory");
        }
        __builtin_amdgcn_s_barrier();      // bounds drift to <1 iter (ring dist 3)
        asm volatile("" ::: "memory");
    }

    // epilogue: verified 16x16 C layout; n uniform per block (image-aligned BM)
    const int off0 = m0 - n_img * HW;
#pragma unroll
    for (int mi = 0; mi < 7; mi++) {
        int off = off0 + wm0 + mi * 16 + lq * 4;    // multiple of 4
#pragma unroll
        for (int nf = 0; nf < 4; nf++) {
            int k = wn0 + nf * 16 + lr;
            *(f32x4*)(out + ((size_t)(n_img * K_OUT + k)) * HW + off) = acc[mi][nf];
        }
    }
}

extern "C" void kernel_launch(void* const* d_in, const int* in_sizes, int n_in,
                              void* d_out, int out_size, void* d_ws, size_t ws_size,
                              hipStream_t stream) {
    const float* x = (const float*)d_in[0];
    const float* w = (const float*)d_in[1];
    float* out = (float*)d_out;

    // Prefer workspace for the bf16 staging arrays: __device__ globals mutated
    // per-iteration force the harness to restore the module image (~150 tiny
    // dispatches ~= 120us/iter). Workspace has no such restore.
    unsigned short* xp_ws = nullptr;
    unsigned short* wt_ws = nullptr;
    if (ws_size >= (size_t)(XP_ELEMS + WT_ELEMS) * sizeof(unsigned short)) {
        xp_ws = (unsigned short*)d_ws;          // 16B-aligned (hip allocations)
        wt_ws = xp_ws + XP_ELEMS;               // XP_ELEMS*2 bytes, mult of 16
    }

    hipLaunchKernelGGL(xpose_x, dim3(H_IN, N_IMG), dim3(256), 0, stream, x, xp_ws);
    hipLaunchKernelGGL(xpose_w, dim3(WT_ELEMS / 256), dim3(256), 0, stream, w, wt_ws);
    hipLaunchKernelGGL(conv_main, dim3(M_TOTAL / BM), dim3(512), 0, stream, out, xp_ws, wt_ws);
}

// Round 9
// 213.118 us; speedup vs baseline: 1.1237x; 1.0379x over previous
//
#include <hip/hip_runtime.h>
#include <cstdint>

#define N_IMG 32
#define C_IN 128
#define H_IN 56
#define W_IN 56
#define K_OUT 256
#define HW (H_IN * W_IN)            // 3136
#define M_TOTAL (N_IMG * HW)        // 100352
#define XP_W 58
#define WT_ELEMS (9 * K_OUT * C_IN)             // 294,912 bf16
#define NKT 36                      // K-steps of 32: 9 rs positions x 4 c-chunks
#define BM 224                      // 4 h-rows of one image (3136/224 = 14 exact)
#define PATCH_PIX (6 * XP_W)        // 348 padded pixels (6 halo rows x 58)
#define PATCH_SHORTS (PATCH_PIX * C_IN)   // 44544 shorts = 87 KiB

typedef __bf16 bf16x8 __attribute__((ext_vector_type(8)));
typedef float f32x4 __attribute__((ext_vector_type(4)));

// NO __device__ globals this round: all staging state lives in d_ws (wt) and
// LDS (patch). Tests whether the stable ~126us dur-vs-conv gap was the harness
// restoring the module's mutated global segment each iteration.

static __device__ __forceinline__ unsigned short f2bf(float f) {
    unsigned int u = __builtin_bit_cast(unsigned int, f);
    u += 0x7fffu + ((u >> 16) & 1u);   // RNE
    return (unsigned short)(u >> 16);
}

// async global->LDS, 16 bytes per lane; LDS dest = wave-uniform base + lane*16
static __device__ __forceinline__ void async_copy16(const unsigned short* g, unsigned short* l) {
    auto gp = (const __attribute__((address_space(1))) unsigned int*)g;
    auto lp = (__attribute__((address_space(3))) unsigned int*)l;
    __builtin_amdgcn_global_load_lds(gp, lp, 16, 0, 0);
}

// ---------------- prep: OIHW fp32 -> wt[rs][k][c] bf16 (workspace) ------------
__global__ __launch_bounds__(256) void xpose_w(const float* __restrict__ w,
                                               unsigned short* __restrict__ wt) {
    int e = blockIdx.x * 256 + threadIdx.x;
    int rr = e >> 15;
    int rem = e & 32767;
    int k = rem >> 7;
    int c = rem & 127;
    wt[e] = f2bf(w[(k * C_IN + c) * 9 + rr]);
}

// ---------------- main: fused-transpose halo-resident-A implicit GEMM ----------
// Identical K-loop/ledger/epilogue to round 8. NEW: the prologue reads the raw
// NCHW fp32 x-slab for this block (6 h-rows incl. halo), transposes it via an
// LDS float scratch (overlaid on Bs slots 2-3, staged later) into the bf16
// NHWC patch with the XOR involution applied at ds_write time. Replaces the
// xpose_x kernel + 27.5MB xp array entirely.
__global__ __launch_bounds__(512, 2) void conv_main(float* __restrict__ out,
                                                    const float* __restrict__ x,
                                                    const unsigned short* __restrict__ wt) {
    __shared__ __align__(16) unsigned short patch[PATCH_SHORTS];
    __shared__ __align__(16) unsigned short Bs[4 * 8192];

    const int tid = threadIdx.x;
    const int wave = tid >> 6, lane = tid & 63;
    const int lr = lane & 15, lq = lane >> 4;
    const int wm0 = (wave & 1) * 112;    // 2 waves in M
    const int wn0 = (wave >> 1) * 64;    // 4 waves in N

    // XCD-aware bijective swizzle: 448 = 8 * 56
    const int bid = blockIdx.x;
    const int gq = (bid & 7) * 56 + (bid >> 3);
    const int m0 = gq * 224;
    const int n_img = gq / 14;            // image (uniform for whole block)
    const int hb = (gq - n_img * 14) * 4; // first output h-row of this block

    // per-lane A pixel bases: patch-local padded pixel index of output pixel
    int qb[7];
#pragma unroll
    for (int mi = 0; mi < 7; mi++) {
        int pp = wm0 + mi * 16 + lr;                 // 0..223
        qb[mi] = (pp / 56 + 1) * XP_W + (pp % 56 + 1);
    }

    // B staging constants: unit u -> row=u>>2, sl=u&3; col pre-swizzled so the
    // linear global_load_lds dest + swizzled ds_read form the same involution.
    const int brow = tid >> 2, bsl = tid & 3;
    const int b_srco  = brow * C_IN + ((bsl ^ ((brow >> 1) & 3)) * 8);
    const int b_srco2 = (128 + brow) * C_IN + ((bsl ^ (((128 + brow) >> 1) & 3)) * 8);
    const int b_ldso = wave * 64 * 8;     // wave-uniform; HW adds lane*16B

    auto stage_B = [&](int kt) {          // 2 global_load_lds per thread
        const unsigned short* src = wt + (kt >> 2) * (K_OUT * C_IN) + (kt & 3) * 32;
        unsigned short* dst = &Bs[(kt & 3) * 8192];
        async_copy16(src + b_srco,  dst + b_ldso);
        async_copy16(src + b_srco2, dst + 4096 + b_ldso);
    };

    // B ds_read swizzled column (shorts)
    const int bswz = (lq ^ ((lr >> 1) & 3)) * 8;

    // ---- fused prologue: zero patch; stage B0,B1; transpose x-slab; B2 ----
    {
#pragma unroll
        for (int i = 0; i < 11; i++) {            // zero all 348 pixels (borders!)
            int u = i * 512 + tid;
            if (u < PATCH_SHORTS / 8)
                *(uint4*)&patch[u * 8] = uint4{0u, 0u, 0u, 0u};
        }
        stage_B(0); stage_B(1);                   // slots 0,1 (scratch is 2-3)

        float* scratch = (float*)&Bs[16384];      // 57*128 floats = 29184B overlay
        const float* __restrict__ xb = x + (size_t)n_img * C_IN * HW;
        for (int hr = 0; hr < 6; hr++) {
            const int h = hb - 1 + hr;            // block-uniform
            __builtin_amdgcn_s_barrier();         // prev hr's scratch reads done
            asm volatile("" ::: "memory");
            if (h >= 0 && h < H_IN) {             // uniform branch
                float v[14];
#pragma unroll
                for (int r = 0; r < 14; r++) {    // 7168 floats, coalesced rows
                    int e = r * 512 + tid;
                    int c = e / 56, w = e - c * 56;
                    v[r] = xb[(c * H_IN + h) * W_IN + w];
                }
#pragma unroll
                for (int r = 0; r < 14; r++) {
                    int e = r * 512 + tid;
                    int c = e / 56, w = e - c * 56;
                    scratch[c * 57 + w] = v[r];
                }
                __builtin_amdgcn_s_barrier();
                asm volatile("" ::: "memory");
#pragma unroll
                for (int rr2 = 0; rr2 < 2; rr2++) {   // 896 pixel-octets
                    int v2 = rr2 * 512 + tid;
                    if (v2 < 896) {
                        int w = v2 >> 4, o = v2 & 15;
                        unsigned int pk[4];
#pragma unroll
                        for (int j = 0; j < 4; j++) {
                            float a = scratch[(o * 8 + 2 * j) * 57 + w];
                            float b = scratch[(o * 8 + 2 * j + 1) * 57 + w];
                            pk[j] = (unsigned int)f2bf(a) | ((unsigned int)f2bf(b) << 16);
                        }
                        int q = hr * XP_W + w + 1;
                        *(uint4*)&patch[q * C_IN + ((o ^ (q & 7)) * 8)] =
                            uint4{pk[0], pk[1], pk[2], pk[3]};
                    }
                }
            }
        }
        __builtin_amdgcn_s_barrier();             // scratch free; patch complete
        asm volatile("" ::: "memory");
        stage_B(2);                               // slot 2 (was scratch)
        asm volatile("s_waitcnt vmcnt(4)" ::: "memory");   // B0 landed; B1,B2 fly
        __builtin_amdgcn_s_barrier();
        asm volatile("" ::: "memory");
    }

    f32x4 acc[7][4];
#pragma unroll
    for (int mi = 0; mi < 7; mi++)
#pragma unroll
        for (int nf = 0; nf < 4; nf++) acc[mi][nf] = f32x4{0.f, 0.f, 0.f, 0.f};

    for (int t = 0; t < NKT; ++t) {
        if (t + 3 < NKT) stage_B(t + 3);   // into ring slot (t+3)&3

        // wave-uniform rs offset into the patch: dq = (r-1)*58 + (s-1)
        const int rs = t >> 2;
        const int r = (rs * 11) >> 5;      // rs/3
        const int s = rs - r * 3;          // rs%3
        const int dq = r * XP_W + s - (XP_W + 1);
        const int so = (t & 3) * 4 + lq;   // logical channel-octet index (0..15)

        bf16x8 bfv[4];
#pragma unroll
        for (int nf = 0; nf < 4; nf++)
            bfv[nf] = *(const bf16x8*)(&Bs[(t & 3) * 8192 + (wn0 + nf * 16 + lr) * 32 + bswz]);
        bf16x8 af[7];
#pragma unroll
        for (int mi = 0; mi < 7; mi++) {
            int qq = qb[mi] + dq;
            af[mi] = *(const bf16x8*)(&patch[qq * C_IN + ((so ^ (qq & 7)) * 8)]);
        }
        // no pinning: compiler interleaves ds_read/MFMA with counted lgkm waits
#pragma unroll
        for (int mi = 0; mi < 7; mi++)
#pragma unroll
            for (int nf = 0; nf < 4; nf++)
                acc[mi][nf] = __builtin_amdgcn_mfma_f32_16x16x32_bf16(
                    af[mi], bfv[nf], acc[mi][nf], 0, 0, 0);

        // counted retire: own B(t+1) pair landed; keep newer pairs in flight
        if (t < NKT - 3) {
            asm volatile("s_waitcnt vmcnt(4)" ::: "memory");
        } else if (t == NKT - 3) {
            asm volatile("s_waitcnt vmcnt(2)" ::: "memory");
        } else {
            asm volatile("s_waitcnt vmcnt(0)" ::: "memory");
        }
        __builtin_amdgcn_s_barrier();      // ring write(t+3) vs read dist = 3
        asm volatile("" ::: "memory");
    }

    // epilogue: verified 16x16 C layout; n uniform per block (image-aligned BM)
    const int off0 = m0 - n_img * HW;
#pragma unroll
    for (int mi = 0; mi < 7; mi++) {
        int off = off0 + wm0 + mi * 16 + lq * 4;    // multiple of 4
#pragma unroll
        for (int nf = 0; nf < 4; nf++) {
            int k = wn0 + nf * 16 + lr;
            *(f32x4*)(out + ((size_t)(n_img * K_OUT + k)) * HW + off) = acc[mi][nf];
        }
    }
}

extern "C" void kernel_launch(void* const* d_in, const int* in_sizes, int n_in,
                              void* d_out, int out_size, void* d_ws, size_t ws_size,
                              hipStream_t stream) {
    const float* x = (const float*)d_in[0];
    const float* w = (const float*)d_in[1];
    float* out = (float*)d_out;

    // wt lives in workspace (1.18 MB; round 8 demonstrated >=28 MB available).
    unsigned short* wt_ws = (unsigned short*)d_ws;

    hipLaunchKernelGGL(xpose_w, dim3(WT_ELEMS / 256), dim3(256), 0, stream, w, wt_ws);
    hipLaunchKernelGGL(conv_main, dim3(M_TOTAL / BM), dim3(512), 0, stream, out, x, wt_ws);
}